// Round 2
// baseline (1089.124 us; speedup 1.0000x reference)
//
#include <hip/hip_runtime.h>
#include <hip/hip_cooperative_groups.h>

namespace cg = cooperative_groups;

// segment_sum: out[receivers[e], :] += edges[e, :]
// E=1,600,000 edges, D_EDGE=50, N_NODES=100,000, fp32.
//
// R7: R4/R5/R6 (three structurally different pipelines) all measure 646-661us
// while the modeled sum of our dispatches is ~150-250us -> the dominant cost is
// invariant: the 8-dispatch structure itself (boundaries/bubbles) and/or fixed
// timed-region overhead. This round fuses ALL phases into ONE cooperative
// kernel (1024 blocks x 256, 4 blocks/CU guaranteed by __launch_bounds__) with
// 5 grid.sync()s. Fallback to the proven multi-kernel path if cooperative
// launch is rejected.

#define N_EDGES   1600000
#define N_GROUPS  (N_EDGES / 4)      // 400000 int4 groups of receivers
#define D_EDGE    50
#define N_NODES   100000
#define NREP      8
#define GRID_B    1024
#define BLK       256
#define SCAN_CHUNK 128
#define NBLK_SCAN ((N_NODES + SCAN_CHUNK - 1) / SCAN_CHUNK)   // 782 (< GRID_B)

// ws layout (bytes)
#define CNT_OFF   0u                  // NREP * 100000 ints = 3,200,000 B
#define CUR_OFF   3200000u            // NREP * 100000 ints
#define OFF_OFF   6400000u            // 100000 ints
#define BSUM_OFF  6800000u            // 1024 ints
#define EIDS_OFF  6804096u            // 1,600,000 ints
#define WS_NEEDED (6804096u + 6400000u)

__device__ __forceinline__ int clamp_node(int r) {
    return (r < 0) ? 0 : ((r >= N_NODES) ? N_NODES - 1 : r);
}

// ===================== fused cooperative kernel =====================
__global__ __launch_bounds__(BLK, 4) void fused_kernel(
    const int* __restrict__ receivers, const float* __restrict__ edges,
    float* __restrict__ out, int* __restrict__ cnt, int* __restrict__ cur,
    int* __restrict__ off, int* __restrict__ bsum, int* __restrict__ eids)
{
    cg::grid_group grid = cg::this_grid();
    const int t  = threadIdx.x;
    const int b  = blockIdx.x;
    const int gt = b * BLK + t;
    const int GT = GRID_B * BLK;                 // 262144 threads

    __shared__ int s_lp[SCAN_CHUNK];             // local exclusive prefix (persists)
    __shared__ int s_sc[SCAN_CHUNK];
    __shared__ int s_red[BLK];

    // ---- phase 0: zero replicated counters ----
    for (int i = gt; i < NREP * N_NODES; i += GT) cnt[i] = 0;
    grid.sync();

    // ---- phase A: histogram (rep = group-index & 7) ----
    const int4* rv4 = (const int4*)receivers;
    for (int idx = gt; idx < N_GROUPS; idx += GT) {
        int4 rv = rv4[idx];
        int* c = cnt + (idx & (NREP - 1)) * N_NODES;
        atomicAdd(&c[clamp_node(rv.x)], 1);
        atomicAdd(&c[clamp_node(rv.y)], 1);
        atomicAdd(&c[clamp_node(rv.z)], 1);
        atomicAdd(&c[clamp_node(rv.w)], 1);
    }
    grid.sync();

    // ---- phase B1: per-block scan of 128 node totals ----
    const int nbase = b * SCAN_CHUNK;
    if (nbase < N_NODES) {
        int total = 0;
        int node = nbase + t;
        if (t < SCAN_CHUNK && node < N_NODES) {
            #pragma unroll
            for (int rep = 0; rep < NREP; ++rep) total += cnt[rep * N_NODES + node];
        }
        if (t < SCAN_CHUNK) s_sc[t] = total;
        __syncthreads();
        for (int ofs = 1; ofs < SCAN_CHUNK; ofs <<= 1) {
            int x = (t >= ofs && t < SCAN_CHUNK) ? s_sc[t - ofs] : 0;
            __syncthreads();
            if (t < SCAN_CHUNK) s_sc[t] += x;
            __syncthreads();
        }
        if (t < SCAN_CHUNK) s_lp[t] = s_sc[t] - total;   // exclusive, kept in LDS
        if (t == SCAN_CHUNK - 1) bsum[b] = s_sc[SCAN_CHUNK - 1];
    }
    grid.sync();

    // ---- phase B3: every block redundantly reduces its base, writes off+cur ----
    if (nbase < N_NODES) {
        int acc = 0;
        for (int j = t; j < b; j += BLK) acc += bsum[j];   // <=4 iters (b<=781)
        s_red[t] = acc;
        __syncthreads();
        for (int ofs = BLK / 2; ofs > 0; ofs >>= 1) {
            if (t < ofs) s_red[t] += s_red[t + ofs];
            __syncthreads();
        }
        int base = s_red[0];
        int node = nbase + t;
        if (t < SCAN_CHUNK && node < N_NODES) {
            int o = base + s_lp[t];
            off[node] = o;
            int run = o;
            #pragma unroll
            for (int rep = 0; rep < NREP; ++rep) {
                cur[rep * N_NODES + node] = run;
                run += cnt[rep * N_NODES + node];
            }
        }
    }
    grid.sync();

    // ---- phase C: scatter edge ids (same idx->rep mapping as phase A) ----
    for (int idx = gt; idx < N_GROUPS; idx += GT) {
        int4 rv = rv4[idx];
        int* c = cur + (idx & (NREP - 1)) * N_NODES;
        int e = idx * 4;
        int p;
        p = atomicAdd(&c[clamp_node(rv.x)], 1); if ((unsigned)p < N_EDGES) eids[p] = e + 0;
        p = atomicAdd(&c[clamp_node(rv.y)], 1); if ((unsigned)p < N_EDGES) eids[p] = e + 1;
        p = atomicAdd(&c[clamp_node(rv.z)], 1); if ((unsigned)p < N_EDGES) eids[p] = e + 2;
        p = atomicAdd(&c[clamp_node(rv.w)], 1); if ((unsigned)p < N_EDGES) eids[p] = e + 3;
    }
    grid.sync();

    // ---- phase D: gather-sum, one wave per node, grid-stride ----
    const int wid  = t >> 6;
    const int lane = t & 63;
    const int l    = (lane < D_EDGE) ? lane : 0;   // inactive lanes alias lane 0
    for (int node = b * 4 + wid; node < N_NODES; node += GRID_B * 4) {
        int startv = off[node];
        int endv   = (node == N_NODES - 1) ? N_EDGES : off[node + 1];
        startv = (startv < 0) ? 0 : startv;
        endv   = (endv > N_EDGES) ? N_EDGES : endv;
        int deg = endv - startv;
        if (deg <= 0) {
            if (lane < D_EDGE) out[node * D_EDGE + lane] = 0.0f;
            continue;
        }
        int last = endv - 1;

        // one per-lane id load covers deg<=64 (P(deg>64) ~ 1e-20 at Poisson(16))
        int idx0 = startv + lane;
        idx0 = (idx0 <= last) ? idx0 : last;
        int eid = eids[idx0];
        eid = (eid < 0 || eid >= N_EDGES) ? 0 : eid;

        float acc = 0.0f;
        int dcap = (deg < 64) ? deg : 64;

#define G16(k) \
        int   e##k = __shfl(eid, j + k); \
        float m##k = (j + k < deg) ? 1.0f : 0.0f; \
        float a##k = edges[e##k * D_EDGE + l];

        for (int j = 0; j < dcap; j += 16) {
            G16(0)  G16(1)  G16(2)  G16(3)
            G16(4)  G16(5)  G16(6)  G16(7)
            G16(8)  G16(9)  G16(10) G16(11)
            G16(12) G16(13) G16(14) G16(15)
            acc += (((a0 + m1 * a1) + (m2 * a2 + m3 * a3))
                  + ((m4 * a4 + m5 * a5) + (m6 * a6 + m7 * a7)))
                 + (((m8 * a8 + m9 * a9) + (m10 * a10 + m11 * a11))
                  + ((m12 * a12 + m13 * a13) + (m14 * a14 + m15 * a15)));
        }
#undef G16

        // rare tail: deg > 64, uniform-load 8-wide masked loop
        for (int j = startv + 64; j < endv; j += 8) {
            int i0 = j + 0, i1 = j + 1, i2 = j + 2, i3 = j + 3;
            int i4 = j + 4, i5 = j + 5, i6 = j + 6, i7 = j + 7;
            float m1 = (i1 <= last) ? 1.0f : 0.0f;
            float m2 = (i2 <= last) ? 1.0f : 0.0f;
            float m3 = (i3 <= last) ? 1.0f : 0.0f;
            float m4 = (i4 <= last) ? 1.0f : 0.0f;
            float m5 = (i5 <= last) ? 1.0f : 0.0f;
            float m6 = (i6 <= last) ? 1.0f : 0.0f;
            float m7 = (i7 <= last) ? 1.0f : 0.0f;
            i1 = (i1 <= last) ? i1 : last;
            i2 = (i2 <= last) ? i2 : last;
            i3 = (i3 <= last) ? i3 : last;
            i4 = (i4 <= last) ? i4 : last;
            i5 = (i5 <= last) ? i5 : last;
            i6 = (i6 <= last) ? i6 : last;
            i7 = (i7 <= last) ? i7 : last;
            int e0 = eids[i0], e1 = eids[i1], e2 = eids[i2], e3 = eids[i3];
            int e4 = eids[i4], e5 = eids[i5], e6 = eids[i6], e7 = eids[i7];
            e0 = (e0 < 0 || e0 >= N_EDGES) ? 0 : e0;
            e1 = (e1 < 0 || e1 >= N_EDGES) ? 0 : e1;
            e2 = (e2 < 0 || e2 >= N_EDGES) ? 0 : e2;
            e3 = (e3 < 0 || e3 >= N_EDGES) ? 0 : e3;
            e4 = (e4 < 0 || e4 >= N_EDGES) ? 0 : e4;
            e5 = (e5 < 0 || e5 >= N_EDGES) ? 0 : e5;
            e6 = (e6 < 0 || e6 >= N_EDGES) ? 0 : e6;
            e7 = (e7 < 0 || e7 >= N_EDGES) ? 0 : e7;
            float a0 = edges[e0 * D_EDGE + l];
            float a1 = edges[e1 * D_EDGE + l];
            float a2 = edges[e2 * D_EDGE + l];
            float a3 = edges[e3 * D_EDGE + l];
            float a4 = edges[e4 * D_EDGE + l];
            float a5 = edges[e5 * D_EDGE + l];
            float a6 = edges[e6 * D_EDGE + l];
            float a7 = edges[e7 * D_EDGE + l];
            acc += ((a0 + m1 * a1) + (m2 * a2 + m3 * a3))
                 + ((m4 * a4 + m5 * a5) + (m6 * a6 + m7 * a7));
        }

        if (lane < D_EDGE) out[node * D_EDGE + lane] = acc;
    }
}

// ===================== fallback multi-kernel path (R6, proven) =====================
__global__ __launch_bounds__(256) void hist_kernel(
    const int* __restrict__ receivers, int* __restrict__ cnt)
{
    int idx = blockIdx.x * 256 + threadIdx.x;
    if (idx * 4 >= N_EDGES) return;
    int4 rv = ((const int4*)receivers)[idx];
    int* c = cnt + (blockIdx.x & (NREP - 1)) * N_NODES;
    atomicAdd(&c[clamp_node(rv.x)], 1);
    atomicAdd(&c[clamp_node(rv.y)], 1);
    atomicAdd(&c[clamp_node(rv.z)], 1);
    atomicAdd(&c[clamp_node(rv.w)], 1);
}

__global__ __launch_bounds__(256) void scan_blocks_kernel(
    const int* __restrict__ cnt, int* __restrict__ off, int* __restrict__ bsum)
{
    __shared__ int s[256];
    int t = threadIdx.x;
    int base = blockIdx.x * 1024 + t * 4;
    int v0 = 0, v1 = 0, v2 = 0, v3 = 0;
    #pragma unroll
    for (int rep = 0; rep < NREP; ++rep) {
        const int* c = cnt + rep * N_NODES;
        if (base + 0 < N_NODES) v0 += c[base + 0];
        if (base + 1 < N_NODES) v1 += c[base + 1];
        if (base + 2 < N_NODES) v2 += c[base + 2];
        if (base + 3 < N_NODES) v3 += c[base + 3];
    }
    int tsum = v0 + v1 + v2 + v3;
    s[t] = tsum;
    __syncthreads();
    for (int ofs = 1; ofs < 256; ofs <<= 1) {
        int x = (t >= ofs) ? s[t - ofs] : 0;
        __syncthreads();
        s[t] += x;
        __syncthreads();
    }
    int excl = s[t] - tsum;
    if (base + 0 < N_NODES) off[base + 0] = excl;
    if (base + 1 < N_NODES) off[base + 1] = excl + v0;
    if (base + 2 < N_NODES) off[base + 2] = excl + v0 + v1;
    if (base + 3 < N_NODES) off[base + 3] = excl + v0 + v1 + v2;
    if (t == 255) bsum[blockIdx.x] = s[255];
}

__global__ __launch_bounds__(128) void scan_bsum_kernel(int* __restrict__ bsum, int n)
{
    __shared__ int s[128];
    int t = threadIdx.x;
    int v = (t < n) ? bsum[t] : 0;
    s[t] = v;
    __syncthreads();
    for (int ofs = 1; ofs < 128; ofs <<= 1) {
        int x = (t >= ofs) ? s[t - ofs] : 0;
        __syncthreads();
        s[t] += x;
        __syncthreads();
    }
    if (t < n) bsum[t] = s[t] - v;
}

__global__ __launch_bounds__(256) void make_cursors_kernel(
    int* __restrict__ off, const int* __restrict__ bsum,
    const int* __restrict__ cnt, int* __restrict__ cur)
{
    int r = blockIdx.x * 256 + threadIdx.x;
    if (r >= N_NODES) return;
    int o = off[r] + bsum[r >> 10];
    off[r] = o;
    int run = o;
    #pragma unroll
    for (int rep = 0; rep < NREP; ++rep) {
        cur[rep * N_NODES + r] = run;
        run += cnt[rep * N_NODES + r];
    }
}

__global__ __launch_bounds__(256) void scatter_ids_kernel(
    const int* __restrict__ receivers, int* __restrict__ cur, int* __restrict__ eids)
{
    int idx = blockIdx.x * 256 + threadIdx.x;
    if (idx * 4 >= N_EDGES) return;
    int4 rv = ((const int4*)receivers)[idx];
    int* c = cur + (blockIdx.x & (NREP - 1)) * N_NODES;
    int e = idx * 4;
    int p;
    p = atomicAdd(&c[clamp_node(rv.x)], 1); if ((unsigned)p < N_EDGES) eids[p] = e + 0;
    p = atomicAdd(&c[clamp_node(rv.y)], 1); if ((unsigned)p < N_EDGES) eids[p] = e + 1;
    p = atomicAdd(&c[clamp_node(rv.z)], 1); if ((unsigned)p < N_EDGES) eids[p] = e + 2;
    p = atomicAdd(&c[clamp_node(rv.w)], 1); if ((unsigned)p < N_EDGES) eids[p] = e + 3;
}

__global__ __launch_bounds__(256) void gather_kernel(
    const float* __restrict__ edges, const int* __restrict__ off,
    const int* __restrict__ eids, float* __restrict__ out)
{
    int node = blockIdx.x * 4 + (threadIdx.x >> 6);
    int lane = threadIdx.x & 63;
    if (node >= N_NODES) return;
    int startv = off[node];
    int endv   = (node == N_NODES - 1) ? N_EDGES : off[node + 1];
    startv = (startv < 0) ? 0 : startv;
    endv   = (endv > N_EDGES) ? N_EDGES : endv;
    int l = (lane < D_EDGE) ? lane : 0;
    int deg = endv - startv;
    if (deg <= 0) {
        if (lane < D_EDGE) out[node * D_EDGE + lane] = 0.0f;
        return;
    }
    int last = endv - 1;
    int idx0 = startv + lane;
    idx0 = (idx0 <= last) ? idx0 : last;
    int eid = eids[idx0];
    eid = (eid < 0 || eid >= N_EDGES) ? 0 : eid;
    float acc = 0.0f;
    int dcap = (deg < 64) ? deg : 64;
#define G16(k) \
    int   e##k = __shfl(eid, j + k); \
    float m##k = (j + k < deg) ? 1.0f : 0.0f; \
    float a##k = edges[e##k * D_EDGE + l];
    for (int j = 0; j < dcap; j += 16) {
        G16(0)  G16(1)  G16(2)  G16(3)
        G16(4)  G16(5)  G16(6)  G16(7)
        G16(8)  G16(9)  G16(10) G16(11)
        G16(12) G16(13) G16(14) G16(15)
        acc += (((a0 + m1 * a1) + (m2 * a2 + m3 * a3))
              + ((m4 * a4 + m5 * a5) + (m6 * a6 + m7 * a7)))
             + (((m8 * a8 + m9 * a9) + (m10 * a10 + m11 * a11))
              + ((m12 * a12 + m13 * a13) + (m14 * a14 + m15 * a15)));
    }
#undef G16
    for (int j = startv + 64; j < endv; j += 8) {
        int i0 = j + 0, i1 = j + 1, i2 = j + 2, i3 = j + 3;
        int i4 = j + 4, i5 = j + 5, i6 = j + 6, i7 = j + 7;
        float m1 = (i1 <= last) ? 1.0f : 0.0f;
        float m2 = (i2 <= last) ? 1.0f : 0.0f;
        float m3 = (i3 <= last) ? 1.0f : 0.0f;
        float m4 = (i4 <= last) ? 1.0f : 0.0f;
        float m5 = (i5 <= last) ? 1.0f : 0.0f;
        float m6 = (i6 <= last) ? 1.0f : 0.0f;
        float m7 = (i7 <= last) ? 1.0f : 0.0f;
        i1 = (i1 <= last) ? i1 : last;
        i2 = (i2 <= last) ? i2 : last;
        i3 = (i3 <= last) ? i3 : last;
        i4 = (i4 <= last) ? i4 : last;
        i5 = (i5 <= last) ? i5 : last;
        i6 = (i6 <= last) ? i6 : last;
        i7 = (i7 <= last) ? i7 : last;
        int e0 = eids[i0], e1 = eids[i1], e2 = eids[i2], e3 = eids[i3];
        int e4 = eids[i4], e5 = eids[i5], e6 = eids[i6], e7 = eids[i7];
        e0 = (e0 < 0 || e0 >= N_EDGES) ? 0 : e0;
        e1 = (e1 < 0 || e1 >= N_EDGES) ? 0 : e1;
        e2 = (e2 < 0 || e2 >= N_EDGES) ? 0 : e2;
        e3 = (e3 < 0 || e3 >= N_EDGES) ? 0 : e3;
        e4 = (e4 < 0 || e4 >= N_EDGES) ? 0 : e4;
        e5 = (e5 < 0 || e5 >= N_EDGES) ? 0 : e5;
        e6 = (e6 < 0 || e6 >= N_EDGES) ? 0 : e6;
        e7 = (e7 < 0 || e7 >= N_EDGES) ? 0 : e7;
        float a0 = edges[e0 * D_EDGE + l];
        float a1 = edges[e1 * D_EDGE + l];
        float a2 = edges[e2 * D_EDGE + l];
        float a3 = edges[e3 * D_EDGE + l];
        float a4 = edges[e4 * D_EDGE + l];
        float a5 = edges[e5 * D_EDGE + l];
        float a6 = edges[e6 * D_EDGE + l];
        float a7 = edges[e7 * D_EDGE + l];
        acc += ((a0 + m1 * a1) + (m2 * a2 + m3 * a3))
             + ((m4 * a4 + m5 * a5) + (m6 * a6 + m7 * a7));
    }
    if (lane < D_EDGE) out[node * D_EDGE + lane] = acc;
}

// ---------------- last-resort fallback: element-wise atomics ----------------
__global__ __launch_bounds__(256) void scatter_add_kernel(
    const float* __restrict__ edges, const int* __restrict__ receivers,
    float* __restrict__ out)
{
    long long t = (long long)blockIdx.x * blockDim.x + threadIdx.x;
    if (t >= (long long)N_EDGES * D_EDGE) return;
    int e = (int)(t / D_EDGE);
    int d = (int)(t - (long long)e * D_EDGE);
    int r = receivers[e];
    r = clamp_node(r);
    atomicAdd(&out[(long long)r * D_EDGE + d], edges[t]);
}

extern "C" void kernel_launch(void* const* d_in, const int* in_sizes, int n_in,
                              void* d_out, int out_size, void* d_ws, size_t ws_size,
                              hipStream_t stream) {
    const float* edges     = (const float*)d_in[1];
    const int*   receivers = (const int*)d_in[2];
    float*       out       = (float*)d_out;

    if (ws_size < WS_NEEDED || d_ws == nullptr) {
        hipMemsetAsync(d_out, 0, (size_t)out_size * sizeof(float), stream);
        const long long total = (long long)N_EDGES * D_EDGE;
        const int grid = (int)((total + 255) / 256);
        scatter_add_kernel<<<grid, 256, 0, stream>>>(edges, receivers, out);
        return;
    }

    char* ws   = (char*)d_ws;
    int*  cnt  = (int*)(ws + CNT_OFF);
    int*  cur  = (int*)(ws + CUR_OFF);
    int*  off  = (int*)(ws + OFF_OFF);
    int*  bsum = (int*)(ws + BSUM_OFF);
    int*  eids = (int*)(ws + EIDS_OFF);

    // -------- preferred: single cooperative dispatch --------
    {
        void* args[] = { (void*)&receivers, (void*)&edges, (void*)&out,
                         (void*)&cnt, (void*)&cur, (void*)&off,
                         (void*)&bsum, (void*)&eids };
        hipError_t err = hipLaunchCooperativeKernel(
            (const void*)fused_kernel, dim3(GRID_B), dim3(BLK), args, 0, stream);
        if (err == hipSuccess) return;
        (void)hipGetLastError();   // clear error, fall through
    }

    // -------- fallback: R6 multi-kernel pipeline --------
    hipMemsetAsync(cnt, 0, (size_t)NREP * N_NODES * sizeof(int), stream);

    const int egrid4 = (N_EDGES / 4 + 255) / 256;            // 1563 blocks
    hist_kernel<<<egrid4, 256, 0, stream>>>(receivers, cnt);

    const int sblocks = (N_NODES + 1023) / 1024;             // 98
    scan_blocks_kernel<<<sblocks, 256, 0, stream>>>(cnt, off, bsum);
    scan_bsum_kernel<<<1, 128, 0, stream>>>(bsum, sblocks);
    make_cursors_kernel<<<(N_NODES + 255) / 256, 256, 0, stream>>>(off, bsum, cnt, cur);

    scatter_ids_kernel<<<egrid4, 256, 0, stream>>>(receivers, cur, eids);

    gather_kernel<<<(N_NODES + 3) / 4, 256, 0, stream>>>(edges, off, eids, out);
}

// Round 3
// 542.264 us; speedup vs baseline: 2.0085x; 2.0085x over previous
//
#include <hip/hip_runtime.h>

// segment_sum: out[receivers[e], :] += edges[e, :]
// E=1,600,000 edges, D_EDGE=50, N_NODES=100,000, fp32.
//
// R8: R7's fused-cooperative experiment exposed the costs: ~300us is fixed
// harness overhead; R6's kernel work was ~347us; device-scope atomics are
// memory-side line RMWs (WRITE_SIZE showed ~148MB of atomic writebacks).
// New structure: bucket decomposition. 4000 buckets x 25 nodes.
//   K1: per-edge returning atomicAdd on a LINE-PADDED bucket cursor (4000
//       lines, ~400 ops/line => ~6us serialization), store packed
//       (edge_id<<5 | local_node). No histogram, no scans, no cursors.
//   K2: one block per bucket: bin edges into per-node lists via fast LDS
//       atomics, then 16-deep pipelined row gather (ids from LDS, no global
//       id latency chain), write out.
// Kernel-work model: ~460MB traffic, 16K waves => ~100-130us (vs R6 ~347us).

#define N_EDGES   1600000
#define N_GROUPS  (N_EDGES / 4)       // 400000 int4 groups of receivers
#define D_EDGE    50
#define N_NODES   100000

#define NBUCK     4000                // buckets
#define NPB       25                  // nodes per bucket (4000*25 = 100000)
#define BCAP      768                 // bucket capacity (mean 400, +18 sigma)
#define LCAP      120                 // per-node list capacity (mean 16)
#define CNT_STRIDE 16                 // pad cursors to one per 64B line

// ws layout (bytes)
#define BCNT_OFF  0u                                   // 4000*16 ints = 256,000 B
#define BIDS_OFF  256000u                              // 4000*768 ints = 12,288,000 B
#define WS_NEEDED (256000u + 12288000u)                // 12,544,000 B

__device__ __forceinline__ int clamp_node(int r) {
    return (r < 0) ? 0 : ((r >= N_NODES) ? N_NODES - 1 : r);
}

// ---------------- K1: bucket scatter ----------------
__global__ __launch_bounds__(256) void bucket_scatter_kernel(
    const int* __restrict__ receivers, int* __restrict__ bcnt, int* __restrict__ bids)
{
    int idx = blockIdx.x * 256 + threadIdx.x;
    if (idx >= N_GROUPS) return;
    int4 rv = ((const int4*)receivers)[idx];
    int e = idx * 4;
#define SCAT1(comp, k)                                                  \
    {                                                                   \
        int r   = clamp_node(rv.comp);                                  \
        int bkt = r / NPB;                 /* magic-mul divide */       \
        int lr  = r - bkt * NPB;                                        \
        int p   = atomicAdd(&bcnt[bkt * CNT_STRIDE], 1);                \
        if ((unsigned)p < BCAP) bids[bkt * BCAP + p] = ((e + k) << 5) | lr; \
    }
    SCAT1(x, 0) SCAT1(y, 1) SCAT1(z, 2) SCAT1(w, 3)
#undef SCAT1
}

// ---------------- K2: bucket gather ----------------
// One block per bucket. Bin ids into per-node LDS lists, then per-wave
// 16-deep pipelined gather-sum.
__global__ __launch_bounds__(256, 8) void bucket_gather_kernel(
    const float* __restrict__ edges, const int* __restrict__ bcnt,
    const int* __restrict__ bids, float* __restrict__ out)
{
    __shared__ int s_list[NPB][LCAP];
    __shared__ int s_lcnt[NPB];

    const int b    = blockIdx.x;
    const int t    = threadIdx.x;
    const int wid  = t >> 6;
    const int lane = t & 63;
    const int l    = (lane < D_EDGE) ? lane : 0;   // inactive lanes alias lane 0

    if (t < NPB) s_lcnt[t] = 0;
    __syncthreads();

    int cnt = bcnt[b * CNT_STRIDE];
    cnt = (cnt < 0) ? 0 : ((cnt > BCAP) ? BCAP : cnt);

    // bin: coalesced read of this bucket's ids, LDS-atomic placement
    for (int i = t; i < cnt; i += 256) {
        int v  = bids[b * BCAP + i];
        int e  = v >> 5;
        int lr = v & 31;
        e  = (e < 0 || e >= N_EDGES) ? 0 : e;       // defensive
        lr = (lr >= NPB) ? NPB - 1 : lr;            // defensive
        int p = atomicAdd(&s_lcnt[lr], 1);
        if (p < LCAP) s_list[lr][p] = e;
    }
    __syncthreads();

    // gather: wave wid handles local nodes wid, wid+4, ...
    const int nodeBase = b * NPB;
    for (int ln = wid; ln < NPB; ln += 4) {
        int node = nodeBase + ln;
        if (node >= N_NODES) break;                  // never taken (4000*25=100000)
        int deg = s_lcnt[ln];
        deg = (deg > LCAP) ? LCAP : deg;
        float acc = 0.0f;

#define G16(k) \
        int   e##k = s_list[ln][(j + k < deg) ? (j + k) : 0]; \
        float m##k = (j + k < deg) ? 1.0f : 0.0f; \
        float a##k = edges[e##k * D_EDGE + l];

        for (int j = 0; j < deg; j += 16) {
            G16(0)  G16(1)  G16(2)  G16(3)
            G16(4)  G16(5)  G16(6)  G16(7)
            G16(8)  G16(9)  G16(10) G16(11)
            G16(12) G16(13) G16(14) G16(15)
            acc += (((m0 * a0 + m1 * a1) + (m2 * a2 + m3 * a3))
                  + ((m4 * a4 + m5 * a5) + (m6 * a6 + m7 * a7)))
                 + (((m8 * a8 + m9 * a9) + (m10 * a10 + m11 * a11))
                  + ((m12 * a12 + m13 * a13) + (m14 * a14 + m15 * a15)));
        }
#undef G16

        if (lane < D_EDGE) out[node * D_EDGE + lane] = acc;
    }
}

// ---------------- last-resort fallback: element-wise atomics ----------------
__global__ __launch_bounds__(256) void scatter_add_kernel(
    const float* __restrict__ edges, const int* __restrict__ receivers,
    float* __restrict__ out)
{
    long long t = (long long)blockIdx.x * blockDim.x + threadIdx.x;
    if (t >= (long long)N_EDGES * D_EDGE) return;
    int e = (int)(t / D_EDGE);
    int d = (int)(t - (long long)e * D_EDGE);
    int r = receivers[e];
    r = clamp_node(r);
    atomicAdd(&out[(long long)r * D_EDGE + d], edges[t]);
}

extern "C" void kernel_launch(void* const* d_in, const int* in_sizes, int n_in,
                              void* d_out, int out_size, void* d_ws, size_t ws_size,
                              hipStream_t stream) {
    const float* edges     = (const float*)d_in[1];
    const int*   receivers = (const int*)d_in[2];
    float*       out       = (float*)d_out;

    if (ws_size < WS_NEEDED || d_ws == nullptr) {
        hipMemsetAsync(d_out, 0, (size_t)out_size * sizeof(float), stream);
        const long long total = (long long)N_EDGES * D_EDGE;
        const int grid = (int)((total + 255) / 256);
        scatter_add_kernel<<<grid, 256, 0, stream>>>(edges, receivers, out);
        return;
    }

    char* ws   = (char*)d_ws;
    int*  bcnt = (int*)(ws + BCNT_OFF);
    int*  bids = (int*)(ws + BIDS_OFF);

    hipMemsetAsync(bcnt, 0, NBUCK * CNT_STRIDE * sizeof(int), stream);   // 256 KB

    const int g1 = (N_GROUPS + 255) / 256;                // 1563 blocks
    bucket_scatter_kernel<<<g1, 256, 0, stream>>>(receivers, bcnt, bids);

    bucket_gather_kernel<<<NBUCK, 256, 0, stream>>>(edges, bcnt, bids, out);
}

// Round 4
// 471.493 us; speedup vs baseline: 2.3099x; 1.1501x over previous
//
#include <hip/hip_runtime.h>

// segment_sum: out[receivers[e], :] += edges[e, :]
// E=1,600,000 edges, D_EDGE=50, N_NODES=100,000, fp32.
//
// R9: R6/R7/R8 triangulation shows global returning atomics cost ~70-140us per
// 1.6M ops REGARDLESS of line spreading -> per-op memory-side throughput limit.
// Fix: cut atomic count 8x via coarse-bucket LDS aggregation.
//   K1: 782 blocks x 2048 edges. Bin edges into 256 coarse-bucket LDS lists
//       (LDS atomics ~free), then ONE global atomicAdd per (block,bucket)
//       reserves a contiguous run in that bucket's region (~200K atomics).
//       Cursors 4-way replicated (rep=blockIdx&3), each replica owns a fixed
//       quarter region -> no cross-replica offset math needed.
//   K2: 256 buckets x 16 slices = 4096 blocks. Stream the bucket's packed ids
//       (bids = 7.9MB -> L3-resident, 16x re-read ~free), filter to the 25-node
//       slice, bin per-node via LDS atomics, then 16-deep pipelined row gather.
// Model: K1 ~15us, K2 ~110us, memset ~2us => kernel work 242 -> ~140us.

#define N_EDGES   1600000
#define N_GROUPS  (N_EDGES / 4)       // 400000 int4 groups of receivers
#define D_EDGE    50
#define N_NODES   100000

#define NBUCK     256                 // coarse buckets
#define NPB_C     391                 // nodes per coarse bucket (256*391 >= 100000)
#define NREPK     4                   // cursor replicas
#define QCAP      1920                // per-(bucket,replica) id capacity (mean 1562, +9sigma)
#define GPB       512                 // int4 groups per K1 block (2048 edges)
#define LCAP1     28                  // K1 per-bucket LDS list cap (mean 8, +7sigma)
#define NSLICE    16                  // K2 slices per bucket
#define SLICE_N   25                  // nodes per slice (16*25=400 >= 391)
#define LCAP2     120                 // per-node list cap (mean 16, Poisson tail ~0)
#define CNT_STRIDE 16                 // one counter per 64B line

// ws layout (bytes)
#define BCNT_OFF  0u                                    // 1024 counters * 64B = 65,536
#define BIDS_OFF  65536u                                // 256*4*1920*4 = 7,864,320
#define WS_NEEDED (65536u + 7864320u)                   // 7,929,856

__device__ __forceinline__ int clamp_node(int r) {
    return (r < 0) ? 0 : ((r >= N_NODES) ? N_NODES - 1 : r);
}

// ---------------- K1: coarse-bucket scatter with LDS aggregation ------------
__global__ __launch_bounds__(256, 4) void bucket_scatter_kernel(
    const int* __restrict__ receivers, int* __restrict__ bcnt, int* __restrict__ bids)
{
    __shared__ int s_list[NBUCK][LCAP1];    // 28,672 B
    __shared__ int s_cnt[NBUCK];            //  1,024 B

    const int t   = threadIdx.x;
    const int b   = blockIdx.x;
    const int rep = b & (NREPK - 1);

    s_cnt[t] = 0;                           // t < 256 == NBUCK
    __syncthreads();

    const int gbase = b * GPB;
    #pragma unroll
    for (int g = 0; g < GPB / 256; ++g) {
        int idx = gbase + g * 256 + t;
        if (idx < N_GROUPS) {
            int4 rv = ((const int4*)receivers)[idx];
            int e = idx * 4;
#define BIN1(comp, k)                                                       \
            {                                                               \
                int r   = clamp_node(rv.comp);                              \
                int bkt = r / NPB_C;                                        \
                int lr  = r - bkt * NPB_C;                                  \
                int v   = ((e + k) << 9) | lr;                              \
                int p   = atomicAdd(&s_cnt[bkt], 1);                        \
                if (p < LCAP1) {                                            \
                    s_list[bkt][p] = v;                                     \
                } else {            /* rare overflow: direct global slot */ \
                    int q = atomicAdd(&bcnt[(bkt * NREPK + rep) * CNT_STRIDE], 1); \
                    if ((unsigned)q < QCAP) bids[(bkt * NREPK + rep) * QCAP + q] = v; \
                }                                                           \
            }
            BIN1(x, 0) BIN1(y, 1) BIN1(z, 2) BIN1(w, 3)
#undef BIN1
        }
    }
    __syncthreads();

    // flush: thread t owns bucket t — one atomic reserves a contiguous run
    int n = s_cnt[t];
    n = (n > LCAP1) ? LCAP1 : n;
    if (n > 0) {
        int base = atomicAdd(&bcnt[(t * NREPK + rep) * CNT_STRIDE], n);
        int* dst = bids + (t * NREPK + rep) * QCAP;
        for (int i = 0; i < n; ++i) {
            int q = base + i;
            if ((unsigned)q < QCAP) dst[q] = s_list[t][i];
        }
    }
}

// ---------------- K2: slice gather ----------------
// Block = (bucket, slice). Stream the bucket's 4 replica segments (L3-hot),
// keep ids whose local node is in this slice, bin per-node in LDS, gather.
__global__ __launch_bounds__(256, 8) void bucket_gather_kernel(
    const float* __restrict__ edges, const int* __restrict__ bcnt,
    const int* __restrict__ bids, float* __restrict__ out)
{
    __shared__ int s_list[SLICE_N][LCAP2];  // 12,000 B
    __shared__ int s_lcnt[SLICE_N];

    const int blk  = blockIdx.x;
    const int bkt  = blk >> 4;              // 0..255
    const int sl   = blk & (NSLICE - 1);    // 0..15
    const int t    = threadIdx.x;
    const int wid  = t >> 6;
    const int lane = t & 63;
    const int l    = (lane < D_EDGE) ? lane : 0;

    if (t < SLICE_N) s_lcnt[t] = 0;
    __syncthreads();

    const int lo = sl * SLICE_N;
    const int hi = lo + SLICE_N;

    #pragma unroll
    for (int rep = 0; rep < NREPK; ++rep) {
        int cnt = bcnt[(bkt * NREPK + rep) * CNT_STRIDE];
        cnt = (cnt < 0) ? 0 : ((cnt > QCAP) ? QCAP : cnt);
        const int* seg = bids + (bkt * NREPK + rep) * QCAP;
        for (int i = t; i < cnt; i += 256) {
            int v  = seg[i];
            int lr = v & 511;
            if (lr >= lo && lr < hi) {
                int e = (int)((unsigned)v >> 9);
                e = (e >= N_EDGES) ? 0 : e;             // defensive
                int p = atomicAdd(&s_lcnt[lr - lo], 1);
                if (p < LCAP2) s_list[lr - lo][p] = e;
            }
        }
    }
    __syncthreads();

    // gather: wave wid handles slice-local nodes wid, wid+4, ...
    for (int ln = wid; ln < SLICE_N; ln += 4) {
        int lrf = lo + ln;
        if (lrf >= NPB_C) continue;                     // slice tail beyond bucket
        int node = bkt * NPB_C + lrf;
        if (node >= N_NODES) continue;                  // last-bucket tail
        int deg = s_lcnt[ln];
        deg = (deg > LCAP2) ? LCAP2 : deg;
        float acc = 0.0f;

#define G16(k) \
        int   e##k = s_list[ln][(j + k < deg) ? (j + k) : 0]; \
        float m##k = (j + k < deg) ? 1.0f : 0.0f; \
        float a##k = edges[e##k * D_EDGE + l];

        for (int j = 0; j < deg; j += 16) {
            G16(0)  G16(1)  G16(2)  G16(3)
            G16(4)  G16(5)  G16(6)  G16(7)
            G16(8)  G16(9)  G16(10) G16(11)
            G16(12) G16(13) G16(14) G16(15)
            acc += (((m0 * a0 + m1 * a1) + (m2 * a2 + m3 * a3))
                  + ((m4 * a4 + m5 * a5) + (m6 * a6 + m7 * a7)))
                 + (((m8 * a8 + m9 * a9) + (m10 * a10 + m11 * a11))
                  + ((m12 * a12 + m13 * a13) + (m14 * a14 + m15 * a15)));
        }
#undef G16

        if (lane < D_EDGE) out[node * D_EDGE + lane] = acc;
    }
}

// ---------------- last-resort fallback: element-wise atomics ----------------
__global__ __launch_bounds__(256) void scatter_add_kernel(
    const float* __restrict__ edges, const int* __restrict__ receivers,
    float* __restrict__ out)
{
    long long t = (long long)blockIdx.x * blockDim.x + threadIdx.x;
    if (t >= (long long)N_EDGES * D_EDGE) return;
    int e = (int)(t / D_EDGE);
    int d = (int)(t - (long long)e * D_EDGE);
    int r = receivers[e];
    r = clamp_node(r);
    atomicAdd(&out[(long long)r * D_EDGE + d], edges[t]);
}

extern "C" void kernel_launch(void* const* d_in, const int* in_sizes, int n_in,
                              void* d_out, int out_size, void* d_ws, size_t ws_size,
                              hipStream_t stream) {
    const float* edges     = (const float*)d_in[1];
    const int*   receivers = (const int*)d_in[2];
    float*       out       = (float*)d_out;

    if (ws_size < WS_NEEDED || d_ws == nullptr) {
        hipMemsetAsync(d_out, 0, (size_t)out_size * sizeof(float), stream);
        const long long total = (long long)N_EDGES * D_EDGE;
        const int grid = (int)((total + 255) / 256);
        scatter_add_kernel<<<grid, 256, 0, stream>>>(edges, receivers, out);
        return;
    }

    char* ws   = (char*)d_ws;
    int*  bcnt = (int*)(ws + BCNT_OFF);
    int*  bids = (int*)(ws + BIDS_OFF);

    hipMemsetAsync(bcnt, 0, NBUCK * NREPK * CNT_STRIDE * sizeof(int), stream);  // 64 KB

    const int g1 = (N_GROUPS + GPB - 1) / GPB;            // 782 blocks
    bucket_scatter_kernel<<<g1, 256, 0, stream>>>(receivers, bcnt, bids);

    bucket_gather_kernel<<<NBUCK * NSLICE, 256, 0, stream>>>(edges, bcnt, bids, out);
}